// Round 1
// baseline (2013.623 us; speedup 1.0000x reference)
//
#include <hip/hip_runtime.h>
#include <math.h>

#define B_ 4
#define L_ 2048
#define C_ 512
#define DI 1024
#define DS 16
#define NTOK 8192
#define SLICE ((long)NTOK * DI)

typedef __attribute__((ext_vector_type(4))) float  f32x4;
typedef __attribute__((ext_vector_type(8))) short  s16x8;
typedef __attribute__((ext_vector_type(8))) __bf16 bf16x8;

__device__ __forceinline__ float bf2f(short s) {
  return __uint_as_float(((unsigned)(unsigned short)s) << 16);
}
__device__ __forceinline__ short f2bf(float f) {
  unsigned u = __float_as_uint(f);
  u += 0x7fffu + ((u >> 16) & 1u);
  return (short)(u >> 16);
}

// ---------------- LayerNorm(x) -> bf16 (one wave per token) ----------------
__global__ __launch_bounds__(256) void ln1_kernel(
    const float* __restrict__ x, const float* __restrict__ g,
    const float* __restrict__ bt, short* __restrict__ out)
{
  int tok  = blockIdx.x * 4 + (threadIdx.x >> 6);
  int lane = threadIdx.x & 63;
  const float* row = x + (long)tok * C_ + lane * 8;
  f32x4 a0 = *(const f32x4*)row, a1 = *(const f32x4*)(row + 4);
  float s = 0.f, q = 0.f;
#pragma unroll
  for (int i = 0; i < 4; ++i) { s += a0[i] + a1[i]; q += a0[i]*a0[i] + a1[i]*a1[i]; }
#pragma unroll
  for (int o = 1; o < 64; o <<= 1) { s += __shfl_xor(s, o); q += __shfl_xor(q, o); }
  float mu = s * (1.f / C_);
  float rs = rsqrtf(q * (1.f / C_) - mu * mu + 1e-5f);
  f32x4 g0 = *(const f32x4*)(g + lane*8), g1 = *(const f32x4*)(g + lane*8 + 4);
  f32x4 b0 = *(const f32x4*)(bt + lane*8), b1 = *(const f32x4*)(bt + lane*8 + 4);
  s16x8 o8;
#pragma unroll
  for (int i = 0; i < 4; ++i) {
    o8[i]     = f2bf((a0[i] - mu) * rs * g0[i] + b0[i]);
    o8[4 + i] = f2bf((a1[i] - mu) * rs * g1[i] + b1[i]);
  }
  *(s16x8*)(out + (long)tok * C_ + lane * 8) = o8;
}

// ------- x_mid = x + 0.5*(y0+y1); LN2(x_mid) -> bf16; x_mid -> f32 -------
__global__ __launch_bounds__(256) void combine_ln2_kernel(
    const float* __restrict__ x, const float* __restrict__ yo,
    const float* __restrict__ g, const float* __restrict__ bt,
    float* __restrict__ xmid, short* __restrict__ xln)
{
  int tok  = blockIdx.x * 4 + (threadIdx.x >> 6);
  int lane = threadIdx.x & 63;
  long base = (long)tok * C_ + lane * 8;
  f32x4 a0 = *(const f32x4*)(x + base),  a1 = *(const f32x4*)(x + base + 4);
  f32x4 p0 = *(const f32x4*)(yo + base), p1 = *(const f32x4*)(yo + base + 4);
  f32x4 q0 = *(const f32x4*)(yo + (long)NTOK * C_ + base);
  f32x4 q1 = *(const f32x4*)(yo + (long)NTOK * C_ + base + 4);
  a0 = a0 + 0.5f * (p0 + q0);
  a1 = a1 + 0.5f * (p1 + q1);
  *(f32x4*)(xmid + base) = a0;
  *(f32x4*)(xmid + base + 4) = a1;
  float s = 0.f, q = 0.f;
#pragma unroll
  for (int i = 0; i < 4; ++i) { s += a0[i] + a1[i]; q += a0[i]*a0[i] + a1[i]*a1[i]; }
#pragma unroll
  for (int o = 1; o < 64; o <<= 1) { s += __shfl_xor(s, o); q += __shfl_xor(q, o); }
  float mu = s * (1.f / C_);
  float rs = rsqrtf(q * (1.f / C_) - mu * mu + 1e-5f);
  f32x4 g0 = *(const f32x4*)(g + lane*8), g1 = *(const f32x4*)(g + lane*8 + 4);
  f32x4 b0 = *(const f32x4*)(bt + lane*8), b1 = *(const f32x4*)(bt + lane*8 + 4);
  s16x8 o8;
#pragma unroll
  for (int i = 0; i < 4; ++i) {
    o8[i]     = f2bf((a0[i] - mu) * rs * g0[i] + b0[i]);
    o8[4 + i] = f2bf((a1[i] - mu) * rs * g1[i] + b1[i]);
  }
  *(s16x8*)(xln + (long)tok * C_ + lane * 8) = o8;
}

// ---------------- depthwise causal/anticausal conv + bias + silu -> bf16 ----------------
// Y layout: 4 slices of (NTOK, DI) f32: [u0, z0, u1, z1]; u slice for dir d at d*2*SLICE.
__global__ __launch_bounds__(256) void conv_silu_kernel(
    const float* __restrict__ Y, const float* __restrict__ cw,
    const float* __restrict__ cb, short* __restrict__ ubf)
{
  int ch = blockIdx.x * 256 + threadIdx.x;   // 0..1023
  int tc = blockIdx.y;                       // 0..15 (chunks of 128)
  int db = blockIdx.z;                       // d*4 + b
  int d = db >> 2, b = db & 3;
  const float* U = Y + (long)d * (2 * SLICE) + (long)b * L_ * DI + ch;
  f32x4 w4 = *(const f32x4*)(cw + ((long)d * DI + ch) * 4);
  float bias = cb[d * DI + ch];
  short* O = ubf + ((long)d * NTOK + (long)b * L_) * DI + ch;
  int t0 = tc * 128;
  if (d == 0) {
    float h3 = (t0 >= 3) ? U[(long)(t0 - 3) * DI] : 0.f;
    float h2 = (t0 >= 2) ? U[(long)(t0 - 2) * DI] : 0.f;
    float h1 = (t0 >= 1) ? U[(long)(t0 - 1) * DI] : 0.f;
    for (int t = t0; t < t0 + 128; ++t) {
      float cur = U[(long)t * DI];
      float v = w4[0]*h3 + w4[1]*h2 + w4[2]*h1 + w4[3]*cur + bias;
      v = v / (1.f + expf(-v));
      O[(long)t * DI] = f2bf(v);
      h3 = h2; h2 = h1; h1 = cur;
    }
  } else {
    // reversed direction in token order: out[t] = w3*x[t]+w2*x[t+1]+w1*x[t+2]+w0*x[t+3]
    float a0v = U[(long)t0 * DI];
    float a1v = (t0 + 1 < L_) ? U[(long)(t0 + 1) * DI] : 0.f;
    float a2v = (t0 + 2 < L_) ? U[(long)(t0 + 2) * DI] : 0.f;
    for (int t = t0; t < t0 + 128; ++t) {
      float a3v = (t + 3 < L_) ? U[(long)(t + 3) * DI] : 0.f;
      float v = w4[3]*a0v + w4[2]*a1v + w4[1]*a2v + w4[0]*a3v + bias;
      v = v / (1.f + expf(-v));
      O[(long)t * DI] = f2bf(v);
      a0v = a1v; a1v = a2v; a2v = a3v;
    }
  }
}

// ---------------- cast x_dbl[:, :32] -> bf16 ----------------
__global__ __launch_bounds__(256) void cast_dtr_kernel(
    const float* __restrict__ xdbl, short* __restrict__ dtr)
{
  long i = (long)blockIdx.x * 256 + threadIdx.x;  // 2*NTOK*32 total
  long n = i >> 5, r = i & 31;
  dtr[i] = f2bf(xdbl[n * 64 + r]);
}

// ---------------- selective scan (thread = dir,b,ch,state) ----------------
__global__ __launch_bounds__(256) void scan_kernel(
    const float* __restrict__ dt,    // dt[d] = dt + d*2*SLICE, (NTOK, DI)
    const short* __restrict__ ubf,   // (2, NTOK, DI) bf16
    const float* __restrict__ xdbl,  // (2, NTOK, 64): [dtr(32) | B(16) | C(16)]
    const float* __restrict__ Yz,    // z[d] = Yz + d*2*SLICE
    const float* __restrict__ Alog, const float* __restrict__ Dp,
    short* __restrict__ yout)
{
  int s  = threadIdx.x & 15;
  int cl = threadIdx.x >> 4;            // 16 channels per block
  int ch = blockIdx.x * 16 + cl;
  int b  = blockIdx.y;
  int d  = blockIdx.z;
  float A  = -expf(Alog[((long)d * DI + ch) * DS + s]);
  float Dv = Dp[d * DI + ch];
  const float* dtp = dt  + (long)d * 2 * SLICE + ((long)b * L_) * DI + ch;
  const short* up  = ubf + ((long)d * NTOK + (long)b * L_) * DI + ch;
  const float* xd  = xdbl + ((long)d * NTOK + (long)b * L_) * 64;
  const float* zp  = Yz  + (long)d * 2 * SLICE + ((long)b * L_) * DI + ch;
  short* yp = yout + ((long)d * NTOK + (long)b * L_) * DI + ch;
  float h = 0.f;
  for (int i = 0; i < L_; ++i) {
    int t = d ? (L_ - 1 - i) : i;
    long off = (long)t * DI;
    float dtv = dtp[off];
    float uv  = bf2f(up[off]);
    float Bv  = xd[(long)t * 64 + 32 + s];
    float Cv  = xd[(long)t * 64 + 48 + s];
    float e = expf(dtv * A);
    h = e * h + (dtv * uv) * Bv;
    float p = h * Cv;
    p += __shfl_xor(p, 1);
    p += __shfl_xor(p, 2);
    p += __shfl_xor(p, 4);
    p += __shfl_xor(p, 8);
    if (s == 0) {
      float z = zp[off];
      float yv = p + uv * Dv;
      float yg = yv * (z / (1.f + expf(-z)));
      yp[off] = f2bf(yg);
    }
  }
}

// ---------------- generic MFMA GEMM: out = X(bf16) @ W(f32->bf16).T ----------------
// EPI: 0 plain f32; 1 GEMM1 4-slice f32; 2 +bias softplus f32; 3 +bias gelu -> bf16; 4 +bias +res -> f32
template <int EPI>
__global__ __launch_bounds__(256) void gemm_bt(
    const short* __restrict__ X, long sX,
    const float* __restrict__ W, long sW,
    const float* __restrict__ bias, long sBias,
    float* __restrict__ outF, long sOutF,
    short* __restrict__ outB,
    const float* __restrict__ res,
    int K, int ncols)
{
  __shared__ short sA[64 * 32];
  __shared__ short sB[64 * 32];
  const int tid  = threadIdx.x;
  const int lane = tid & 63;
  const int w    = tid >> 6;
  const int d    = blockIdx.z;
  const int m0   = blockIdx.x * 64;
  const int n0   = blockIdx.y * 64;
  const short* Xp = X + (long)d * sX;
  const float* Wp = W + (long)d * sW;

  f32x4 acc[4] = {};
  const int srow = tid >> 2;   // 0..63
  const int skg  = tid & 3;    // 0..3
  const int sbyte = ((srow * 64 + skg * 16) ^ ((srow & 7) << 4));

  const int arow  = w * 16 + (lane & 15);
  const int kg    = lane >> 4;
  const int abyte = ((arow * 64 + kg * 16) ^ ((arow & 7) << 4));

  for (int k0 = 0; k0 < K; k0 += 32) {
    { // A tile: bf16 activations
      const short* src = Xp + (long)(m0 + srow) * K + k0 + skg * 8;
      s16x8 v = *reinterpret_cast<const s16x8*>(src);
      *reinterpret_cast<s16x8*>(reinterpret_cast<char*>(sA) + sbyte) = v;
    }
    { // B tile: fp32 weights -> bf16
      const float* src = Wp + (long)(n0 + srow) * K + k0 + skg * 8;
      f32x4 f0 = *reinterpret_cast<const f32x4*>(src);
      f32x4 f1 = *reinterpret_cast<const f32x4*>(src + 4);
      s16x8 v;
#pragma unroll
      for (int i = 0; i < 4; ++i) { v[i] = f2bf(f0[i]); v[4 + i] = f2bf(f1[i]); }
      *reinterpret_cast<s16x8*>(reinterpret_cast<char*>(sB) + sbyte) = v;
    }
    __syncthreads();
    s16x8 af = *reinterpret_cast<const s16x8*>(reinterpret_cast<char*>(sA) + abyte);
#pragma unroll
    for (int nt = 0; nt < 4; ++nt) {
      int brow = nt * 16 + (lane & 15);
      int bbyte = ((brow * 64 + kg * 16) ^ ((brow & 7) << 4));
      s16x8 bf = *reinterpret_cast<const s16x8*>(reinterpret_cast<char*>(sB) + bbyte);
      acc[nt] = __builtin_amdgcn_mfma_f32_16x16x32_bf16(
          __builtin_bit_cast(bf16x8, af), __builtin_bit_cast(bf16x8, bf), acc[nt], 0, 0, 0);
    }
    __syncthreads();
  }

  const int col0 = lane & 15;
  const int rsub = (lane >> 4) * 4;
#pragma unroll
  for (int nt = 0; nt < 4; ++nt) {
    int col = n0 + nt * 16 + col0;
#pragma unroll
    for (int j = 0; j < 4; ++j) {
      int row = m0 + w * 16 + rsub + j;
      float v = acc[nt][j];
      if (EPI == 0) {
        outF[(long)d * sOutF + (long)row * ncols + col] = v;
      } else if (EPI == 1) {
        int slice = col >> 10, c = col & 1023;
        outF[(long)slice * SLICE + (long)row * DI + c] = v;
      } else if (EPI == 2) {
        v += bias[(long)d * sBias + col];
        v = (v > 20.f) ? v : log1pf(expf(v));
        outF[(long)d * sOutF + (long)row * ncols + col] = v;
      } else if (EPI == 3) {
        v += bias[col];
        v = 0.5f * v * (1.f + erff(v * 0.70710678118654752f));
        outB[(long)row * ncols + col] = f2bf(v);
      } else if (EPI == 4) {
        v += bias[col] + res[(long)row * ncols + col];
        outF[(long)row * ncols + col] = v;
      }
    }
  }
}

extern "C" void kernel_launch(void* const* d_in, const int* in_sizes, int n_in,
                              void* d_out, int out_size, void* d_ws, size_t ws_size,
                              hipStream_t stream) {
  const float* x      = (const float*)d_in[0];
  const float* gamma1 = (const float*)d_in[1];
  const float* beta1  = (const float*)d_in[2];
  const float* W_in   = (const float*)d_in[3];
  const float* conv_w = (const float*)d_in[4];
  const float* conv_b = (const float*)d_in[5];
  const float* W_xprj = (const float*)d_in[6];
  const float* W_dt   = (const float*)d_in[7];
  const float* b_dt   = (const float*)d_in[8];
  const float* A_log  = (const float*)d_in[9];
  const float* Dp     = (const float*)d_in[10];
  const float* W_out  = (const float*)d_in[11];
  const float* gamma2 = (const float*)d_in[12];
  const float* beta2  = (const float*)d_in[13];
  const float* W1     = (const float*)d_in[14];
  const float* b1     = (const float*)d_in[15];
  const float* W2     = (const float*)d_in[16];
  const float* b2     = (const float*)d_in[17];
  float* out = (float*)d_out;

  char* ws = (char*)d_ws;
  short* xnbf  = (short*)ws;                               // 8 MB
  float* Y     = (float*)(ws + (8L << 20));                // 128 MB: [u0,z0,u1,z1] each (NTOK,DI)
  short* ubf   = (short*)(ws + (136L << 20));              // 32 MB (2,NTOK,DI) bf16
  float* xdbl  = (float*)(ws + (168L << 20));              // 4 MB (2,NTOK,64)
  short* dtr   = (short*)(ws + (172L << 20));              // 1 MB (2,NTOK,32) bf16
  short* yinner= (short*)(ws + (173L << 20));              // 32 MB (2,NTOK,DI) bf16
  float* Yz0   = Y + SLICE;          // z slices base; also reused for yo after scan
  float* xmid  = Y + 3 * SLICE;      // reuse z1 slice after scan
  short* xln   = (short*)(xmid + (long)NTOK * C_);

  // 1. LN1 -> bf16
  ln1_kernel<<<NTOK / 4, 256, 0, stream>>>(x, gamma1, beta1, xnbf);
  // 2. in_proj for both dirs fused: (8192,512)x(4096,512)^T -> sliced [u0,z0,u1,z1]
  gemm_bt<1><<<dim3(128, 64, 1), 256, 0, stream>>>(xnbf, 0, W_in, 0, nullptr, 0,
                                                   Y, 0, nullptr, nullptr, C_, 4096);
  // 3. depthwise conv + silu -> u bf16
  conv_silu_kernel<<<dim3(4, 16, 8), 256, 0, stream>>>(Y, conv_w, conv_b, ubf);
  // 4. x_proj: (8192,1024)x(64,1024)^T per dir -> x_dbl f32
  gemm_bt<0><<<dim3(128, 1, 2), 256, 0, stream>>>(ubf, (long)NTOK * DI, W_xprj, 64L * DI,
                                                  nullptr, 0, xdbl, (long)NTOK * 64,
                                                  nullptr, nullptr, DI, 64);
  // 5. cast dt_rank slice to bf16
  cast_dtr_kernel<<<2048, 256, 0, stream>>>(xdbl, dtr);
  // 6. dt_proj + softplus -> dt f32 (overwrites consumed u_raw slices of Y)
  gemm_bt<2><<<dim3(128, 16, 2), 256, 0, stream>>>(dtr, (long)NTOK * 32, W_dt, (long)DI * 32,
                                                   b_dt, DI, Y, 2 * SLICE,
                                                   nullptr, nullptr, 32, DI);
  // 7. selective scan (+u*D, *silu(z)) -> yinner bf16
  scan_kernel<<<dim3(64, 4, 2), 256, 0, stream>>>(Y, ubf, xdbl, Yz0, A_log, Dp, yinner);
  // 8. out_proj per dir -> yo f32 (overwrites consumed z0 slice)
  gemm_bt<0><<<dim3(128, 8, 2), 256, 0, stream>>>(yinner, (long)NTOK * DI, W_out, (long)C_ * DI,
                                                  nullptr, 0, Yz0, (long)NTOK * C_,
                                                  nullptr, nullptr, DI, C_);
  // 9. residual combine + LN2
  combine_ln2_kernel<<<NTOK / 4, 256, 0, stream>>>(x, Yz0, gamma2, beta2, xmid, xln);
  // 10. MLP up + gelu(exact) -> H bf16 (reuses ubf)
  gemm_bt<3><<<dim3(128, 32, 1), 256, 0, stream>>>(xln, 0, W1, 0, b1, 0,
                                                   nullptr, 0, ubf, nullptr, C_, 4 * C_);
  // 11. MLP down + bias + residual -> out f32
  gemm_bt<4><<<dim3(128, 8, 1), 256, 0, stream>>>(ubf, 0, W2, 0, b2, 0,
                                                  out, 0, nullptr, xmid, 4 * C_, C_);
}

// Round 2
// 664.075 us; speedup vs baseline: 3.0322x; 3.0322x over previous
//
#include <hip/hip_runtime.h>
#include <math.h>

#define B_ 4
#define L_ 2048
#define C_ 512
#define DI 1024
#define DS 16
#define NTOK 8192
#define SLICE ((long)NTOK * DI)
#define T_ 64
#define NC_ 32

typedef __attribute__((ext_vector_type(4))) float  f32x4;
typedef __attribute__((ext_vector_type(8))) short  s16x8;
typedef __attribute__((ext_vector_type(8))) __bf16 bf16x8;

__device__ __forceinline__ float bf2f(short s) {
  return __uint_as_float(((unsigned)(unsigned short)s) << 16);
}
__device__ __forceinline__ short f2bf(float f) {
  unsigned u = __float_as_uint(f);
  u += 0x7fffu + ((u >> 16) & 1u);
  return (short)(u >> 16);
}

// ---------------- LayerNorm(x) -> bf16 (one wave per token) ----------------
__global__ __launch_bounds__(256) void ln1_kernel(
    const float* __restrict__ x, const float* __restrict__ g,
    const float* __restrict__ bt, short* __restrict__ out)
{
  int tok  = blockIdx.x * 4 + (threadIdx.x >> 6);
  int lane = threadIdx.x & 63;
  const float* row = x + (long)tok * C_ + lane * 8;
  f32x4 a0 = *(const f32x4*)row, a1 = *(const f32x4*)(row + 4);
  float s = 0.f, q = 0.f;
#pragma unroll
  for (int i = 0; i < 4; ++i) { s += a0[i] + a1[i]; q += a0[i]*a0[i] + a1[i]*a1[i]; }
#pragma unroll
  for (int o = 1; o < 64; o <<= 1) { s += __shfl_xor(s, o); q += __shfl_xor(q, o); }
  float mu = s * (1.f / C_);
  float rs = rsqrtf(q * (1.f / C_) - mu * mu + 1e-5f);
  f32x4 g0 = *(const f32x4*)(g + lane*8), g1 = *(const f32x4*)(g + lane*8 + 4);
  f32x4 b0 = *(const f32x4*)(bt + lane*8), b1 = *(const f32x4*)(bt + lane*8 + 4);
  s16x8 o8;
#pragma unroll
  for (int i = 0; i < 4; ++i) {
    o8[i]     = f2bf((a0[i] - mu) * rs * g0[i] + b0[i]);
    o8[4 + i] = f2bf((a1[i] - mu) * rs * g1[i] + b1[i]);
  }
  *(s16x8*)(out + (long)tok * C_ + lane * 8) = o8;
}

// ------- x_mid = x + 0.5*(y0+y1); LN2(x_mid) -> bf16; x_mid -> f32 -------
__global__ __launch_bounds__(256) void combine_ln2_kernel(
    const float* __restrict__ x, const float* __restrict__ yo,
    const float* __restrict__ g, const float* __restrict__ bt,
    float* __restrict__ xmid, short* __restrict__ xln)
{
  int tok  = blockIdx.x * 4 + (threadIdx.x >> 6);
  int lane = threadIdx.x & 63;
  long base = (long)tok * C_ + lane * 8;
  f32x4 a0 = *(const f32x4*)(x + base),  a1 = *(const f32x4*)(x + base + 4);
  f32x4 p0 = *(const f32x4*)(yo + base), p1 = *(const f32x4*)(yo + base + 4);
  f32x4 q0 = *(const f32x4*)(yo + (long)NTOK * C_ + base);
  f32x4 q1 = *(const f32x4*)(yo + (long)NTOK * C_ + base + 4);
  a0 = a0 + 0.5f * (p0 + q0);
  a1 = a1 + 0.5f * (p1 + q1);
  *(f32x4*)(xmid + base) = a0;
  *(f32x4*)(xmid + base + 4) = a1;
  float s = 0.f, q = 0.f;
#pragma unroll
  for (int i = 0; i < 4; ++i) { s += a0[i] + a1[i]; q += a0[i]*a0[i] + a1[i]*a1[i]; }
#pragma unroll
  for (int o = 1; o < 64; o <<= 1) { s += __shfl_xor(s, o); q += __shfl_xor(q, o); }
  float mu = s * (1.f / C_);
  float rs = rsqrtf(q * (1.f / C_) - mu * mu + 1e-5f);
  f32x4 g0 = *(const f32x4*)(g + lane*8), g1 = *(const f32x4*)(g + lane*8 + 4);
  f32x4 b0 = *(const f32x4*)(bt + lane*8), b1 = *(const f32x4*)(bt + lane*8 + 4);
  s16x8 o8;
#pragma unroll
  for (int i = 0; i < 4; ++i) {
    o8[i]     = f2bf((a0[i] - mu) * rs * g0[i] + b0[i]);
    o8[4 + i] = f2bf((a1[i] - mu) * rs * g1[i] + b1[i]);
  }
  *(s16x8*)(xln + (long)tok * C_ + lane * 8) = o8;
}

// ------- depthwise conv + bias + silu; reads u slices (d,n,ch) f32, writes u_tr (d,ch,n) bf16 -------
__global__ __launch_bounds__(256) void conv_silu_kernel(
    const float* __restrict__ YU, const float* __restrict__ cw,
    const float* __restrict__ cb, short* __restrict__ u_tr)
{
  int ch = blockIdx.x * 256 + threadIdx.x;   // 0..1023
  int tc = blockIdx.y;                       // 0..15 (chunks of 128)
  int db = blockIdx.z;                       // d*4 + b
  int d = db >> 2, b = db & 3;
  const float* U = YU + (long)d * SLICE + (long)b * L_ * DI + ch;
  f32x4 w4 = *(const f32x4*)(cw + ((long)d * DI + ch) * 4);
  float bias = cb[d * DI + ch];
  short* O = u_tr + ((long)d * DI + ch) * NTOK + (long)b * L_;
  int t0 = tc * 128;
  s16x8 buf;
  if (d == 0) {
    float h3 = (t0 >= 3) ? U[(long)(t0 - 3) * DI] : 0.f;
    float h2 = (t0 >= 2) ? U[(long)(t0 - 2) * DI] : 0.f;
    float h1 = (t0 >= 1) ? U[(long)(t0 - 1) * DI] : 0.f;
    for (int t = t0; t < t0 + 128; ++t) {
      float cur = U[(long)t * DI];
      float v = w4[0]*h3 + w4[1]*h2 + w4[2]*h1 + w4[3]*cur + bias;
      v = v / (1.f + expf(-v));
      buf[t & 7] = f2bf(v);
      if ((t & 7) == 7) *(s16x8*)(O + t - 7) = buf;
      h3 = h2; h2 = h1; h1 = cur;
    }
  } else {
    float a0v = U[(long)t0 * DI];
    float a1v = (t0 + 1 < L_) ? U[(long)(t0 + 1) * DI] : 0.f;
    float a2v = (t0 + 2 < L_) ? U[(long)(t0 + 2) * DI] : 0.f;
    for (int t = t0; t < t0 + 128; ++t) {
      float a3v = (t + 3 < L_) ? U[(long)(t + 3) * DI] : 0.f;
      float v = w4[3]*a0v + w4[2]*a1v + w4[1]*a2v + w4[0]*a3v + bias;
      v = v / (1.f + expf(-v));
      buf[t & 7] = f2bf(v);
      if ((t & 7) == 7) *(s16x8*)(O + t - 7) = buf;
      a0v = a1v; a1v = a2v; a2v = a3v;
    }
  }
}

// ---------------- selective scan, 2-pass chunked ----------------
// PASS 0: per-chunk partial (h0=0) -> hbuf (h_end), Sbuf (sum dt)
// PASS 1: final with h_in from hbuf; writes y (gated) bf16 in-place over u_tr
template <int PASS, int DIR>
__global__ __launch_bounds__(256) void scan_pass(
    const float* __restrict__ dt_tr, const short* __restrict__ u_tr,
    const float* __restrict__ xdbl, const float* __restrict__ z_tr,
    const float* __restrict__ Alog, const float* __restrict__ Dp,
    float* __restrict__ hbuf, float* __restrict__ Sbuf, short* __restrict__ y_tr)
{
  __shared__ float sBC[T_ * 32];
  const int tid = threadIdx.x;
  const int ch  = blockIdx.x * 256 + tid;
  const int c   = blockIdx.y;
  const int b   = blockIdx.z;
  const int d   = DIR;
  const int db  = d * 4 + b;
  const long n0 = (long)b * L_ + c * T_;
  const float* xrow = xdbl + ((long)d * NTOK + n0) * 64 + 32;
  if (PASS == 0) {  // stage B only: [T_][16]
    int r = tid >> 2, cc = (tid & 3) * 4;
    *(f32x4*)&sBC[r * 16 + cc] = *(const f32x4*)(xrow + (long)r * 64 + cc);
  } else {          // stage B|C: [T_][32]
    int r = tid >> 2, cc = (tid & 3) * 8;
    *(f32x4*)&sBC[r * 32 + cc]     = *(const f32x4*)(xrow + (long)r * 64 + cc);
    *(f32x4*)&sBC[r * 32 + cc + 4] = *(const f32x4*)(xrow + (long)r * 64 + cc + 4);
  }
  __syncthreads();
  float A2[16];
  {
    const float* Ap = Alog + ((long)d * DI + ch) * DS;
#pragma unroll
    for (int s = 0; s < 16; ++s) A2[s] = -expf(Ap[s]) * 1.4426950408889634f;
  }
  const long chbase = ((long)d * DI + ch) * NTOK + n0;
  const float* dtp = dt_tr + chbase;
  const short* up  = u_tr + chbase;
  const float* zp  = z_tr + chbase;
  short* yp = y_tr + chbase;
  const long hb = (((long)db * NC_ + c) * DI + ch) * 16;
  float h[16];
  float Dv = 0.f;
  if (PASS == 1) {
#pragma unroll
    for (int s = 0; s < 16; s += 4) *(f32x4*)&h[s] = *(const f32x4*)&hbuf[hb + s];
    Dv = Dp[d * DI + ch];
  } else {
#pragma unroll
    for (int s = 0; s < 16; ++s) h[s] = 0.f;
  }
  float S = 0.f;
  f32x4 dA, dB2f, zA, zB; s16x8 u8;
  f32x4 dAn, dBn, zAn, zBn; s16x8 u8n;
  const int t0_first = DIR ? (T_ - 8) : 0;
  dA   = *(const f32x4*)(dtp + t0_first);
  dB2f = *(const f32x4*)(dtp + t0_first + 4);
  u8   = *(const s16x8*)(up + t0_first);
  if (PASS == 1) { zA = *(const f32x4*)(zp + t0_first); zB = *(const f32x4*)(zp + t0_first + 4); }
#pragma unroll
  for (int ib = 0; ib < T_ / 8; ++ib) {
    const int t0 = DIR ? (T_ - 8 - ib * 8) : ib * 8;
    if (ib + 1 < T_ / 8) {
      const int t1 = DIR ? (T_ - 16 - ib * 8) : (ib * 8 + 8);
      dAn = *(const f32x4*)(dtp + t1);
      dBn = *(const f32x4*)(dtp + t1 + 4);
      u8n = *(const s16x8*)(up + t1);
      if (PASS == 1) { zAn = *(const f32x4*)(zp + t1); zBn = *(const f32x4*)(zp + t1 + 4); }
    }
    s16x8 y8;
#pragma unroll
    for (int jj = 0; jj < 8; ++jj) {
      const int j = DIR ? (7 - jj) : jj;
      float dtv = (j < 4) ? dA[j] : dB2f[j - 4];
      float uv  = bf2f(u8[j]);
      float w = dtv * uv;
      const float* bc = &sBC[(t0 + j) * (PASS ? 32 : 16)];
      float p = 0.f;
#pragma unroll
      for (int s = 0; s < 16; ++s) {
        float e = exp2f(dtv * A2[s]);
        h[s] = e * h[s] + w * bc[s];
        if (PASS == 1) p += h[s] * bc[16 + s];
      }
      if (PASS == 0) {
        S += dtv;
      } else {
        float z = (j < 4) ? zA[j] : zB[j - 4];
        float yv = p + uv * Dv;
        y8[j] = f2bf(yv * (z / (1.f + expf(-z))));
      }
    }
    if (PASS == 1) *(s16x8*)(yp + t0) = y8;
    if (ib + 1 < T_ / 8) {
      dA = dAn; dB2f = dBn; u8 = u8n;
      if (PASS == 1) { zA = zAn; zB = zBn; }
    }
  }
  if (PASS == 0) {
#pragma unroll
    for (int s = 0; s < 16; s += 4) *(f32x4*)&hbuf[hb + s] = *(const f32x4*)&h[s];
    Sbuf[((long)db * NC_ + c) * DI + ch] = S;
  }
}

// ---------------- chunk combine: hbuf hend -> hin ----------------
__global__ __launch_bounds__(256) void scan_combine(
    const float* __restrict__ Alog, float* __restrict__ hbuf,
    const float* __restrict__ Sbuf)
{
  int tid = threadIdx.x;
  int ch = (blockIdx.x & 3) * 256 + tid;
  int db = blockIdx.x >> 2;     // 0..7
  int d = db >> 2;
  float A2[16];
  const float* Ap = Alog + ((long)d * DI + ch) * DS;
#pragma unroll
  for (int s = 0; s < 16; ++s) A2[s] = -expf(Ap[s]) * 1.4426950408889634f;
  float h[16];
#pragma unroll
  for (int s = 0; s < 16; ++s) h[s] = 0.f;
  for (int cc = 0; cc < NC_; ++cc) {
    int c = (d == 1) ? (NC_ - 1 - cc) : cc;
    long hb = (((long)db * NC_ + c) * DI + ch) * 16;
    float S = Sbuf[((long)db * NC_ + c) * DI + ch];
    float he[16];
#pragma unroll
    for (int s = 0; s < 16; s += 4) *(f32x4*)&he[s] = *(const f32x4*)&hbuf[hb + s];
#pragma unroll
    for (int s = 0; s < 16; s += 4) *(f32x4*)&hbuf[hb + s] = *(const f32x4*)&h[s];
#pragma unroll
    for (int s = 0; s < 16; ++s) h[s] = exp2f(A2[s] * S) * h[s] + he[s];
  }
}

// ---------------- generic MFMA GEMM: out = X(bf16) @ W(f32->bf16).T ----------------
// ATR: A stored transposed as [K_rows][NTOK] bf16 (lda = NTOK), sX = per-d slice stride
// EPI: 0 plain f32; 1 in_proj split (u slices + z transposed); 2 +bias softplus -> transposed f32;
//      3 +bias gelu -> bf16; 4 +bias +res -> f32; 5 x_proj split (dtr bf16 + xdbl f32)
template <int EPI, int ATR>
__global__ __launch_bounds__(256) void gemm_bt(
    const short* __restrict__ X, long sX,
    const float* __restrict__ W, long sW,
    const float* __restrict__ bias, long sBias,
    float* __restrict__ outF, long sOutF,
    short* __restrict__ outB,
    const float* __restrict__ res,
    float* __restrict__ outF2,
    int K, int ncols)
{
  __shared__ short sA[64 * 32];
  __shared__ short sB[64 * 32];
  const int tid  = threadIdx.x;
  const int lane = tid & 63;
  const int w    = tid >> 6;
  const int d    = blockIdx.z;
  const int m0   = blockIdx.x * 64;
  const int n0   = blockIdx.y * 64;
  const short* Xp = X + (long)d * sX;
  const float* Wp = W + (long)d * sW;

  f32x4 acc[4] = {};
  const int srow = tid >> 2;   // 0..63
  const int skg  = tid & 3;    // 0..3
  const int sbyte = ((srow * 64 + skg * 16) ^ ((srow & 7) << 4));

  const int arow  = w * 16 + (lane & 15);
  const int kg    = lane >> 4;
  const int abyte = ((arow * 64 + kg * 16) ^ ((arow & 7) << 4));

  for (int k0 = 0; k0 < K; k0 += 32) {
    if (ATR) {  // A stored [k][n]: scatter-transpose into swizzled LDS tile
      const int krow = tid & 31;
      const int mc0  = (tid >> 5) * 8;
      const short* src = Xp + (long)(k0 + krow) * NTOK + m0 + mc0;
      s16x8 v = *reinterpret_cast<const s16x8*>(src);
#pragma unroll
      for (int j = 0; j < 8; ++j) {
        int m = mc0 + j;
        int byte_off = ((m * 64 + krow * 2) ^ ((m & 7) << 4));
        *reinterpret_cast<short*>(reinterpret_cast<char*>(sA) + byte_off) = v[j];
      }
    } else {
      const short* src = Xp + (long)(m0 + srow) * K + k0 + skg * 8;
      s16x8 v = *reinterpret_cast<const s16x8*>(src);
      *reinterpret_cast<s16x8*>(reinterpret_cast<char*>(sA) + sbyte) = v;
    }
    { // B tile: fp32 weights -> bf16
      const float* src = Wp + (long)(n0 + srow) * K + k0 + skg * 8;
      f32x4 f0 = *reinterpret_cast<const f32x4*>(src);
      f32x4 f1 = *reinterpret_cast<const f32x4*>(src + 4);
      s16x8 v;
#pragma unroll
      for (int i = 0; i < 4; ++i) { v[i] = f2bf(f0[i]); v[4 + i] = f2bf(f1[i]); }
      *reinterpret_cast<s16x8*>(reinterpret_cast<char*>(sB) + sbyte) = v;
    }
    __syncthreads();
    s16x8 af = *reinterpret_cast<const s16x8*>(reinterpret_cast<char*>(sA) + abyte);
#pragma unroll
    for (int nt = 0; nt < 4; ++nt) {
      int brow = nt * 16 + (lane & 15);
      int bbyte = ((brow * 64 + kg * 16) ^ ((brow & 7) << 4));
      s16x8 bf = *reinterpret_cast<const s16x8*>(reinterpret_cast<char*>(sB) + bbyte);
      acc[nt] = __builtin_amdgcn_mfma_f32_16x16x32_bf16(
          __builtin_bit_cast(bf16x8, af), __builtin_bit_cast(bf16x8, bf), acc[nt], 0, 0, 0);
    }
    __syncthreads();
  }

  const int col0 = lane & 15;
  const int rsub = (lane >> 4) * 4;
  const int row0 = m0 + w * 16 + rsub;
#pragma unroll
  for (int nt = 0; nt < 4; ++nt) {
    int col = n0 + nt * 16 + col0;
    if (EPI == 1) {
      int slice = col >> 10, c = col & 1023;
      if (slice & 1) {          // z -> transposed f32x4 (4 consecutive rows)
        int dz = slice >> 1;
        *(f32x4*)&outF2[((long)dz * DI + c) * NTOK + row0] = acc[nt];
      } else {                  // u -> (n, ch) f32
        int du = slice >> 1;
#pragma unroll
        for (int j = 0; j < 4; ++j)
          outF[(long)du * SLICE + (long)(row0 + j) * DI + c] = acc[nt][j];
      }
    } else if (EPI == 2) {      // softplus -> dt_tr transposed
      float bv = bias[(long)d * sBias + col];
      f32x4 v4;
#pragma unroll
      for (int j = 0; j < 4; ++j) {
        float v = acc[nt][j] + bv;
        v4[j] = (v > 20.f) ? v : log1pf(expf(v));
      }
      *(f32x4*)&outF[((long)d * DI + col) * NTOK + row0] = v4;
    } else {
#pragma unroll
      for (int j = 0; j < 4; ++j) {
        int row = row0 + j;
        float v = acc[nt][j];
        if (EPI == 0) {
          outF[(long)d * sOutF + (long)row * ncols + col] = v;
        } else if (EPI == 3) {
          v += bias[col];
          v = 0.5f * v * (1.f + erff(v * 0.70710678118654752f));
          outB[(long)row * ncols + col] = f2bf(v);
        } else if (EPI == 4) {
          v += bias[col] + res[(long)row * ncols + col];
          outF[(long)row * ncols + col] = v;
        } else if (EPI == 5) {
          if (col < 32) outB[((long)d * NTOK + row) * 32 + col] = f2bf(v);
          else          outF[((long)d * NTOK + row) * 64 + col] = v;
        }
      }
    }
  }
}

extern "C" void kernel_launch(void* const* d_in, const int* in_sizes, int n_in,
                              void* d_out, int out_size, void* d_ws, size_t ws_size,
                              hipStream_t stream) {
  const float* x      = (const float*)d_in[0];
  const float* gamma1 = (const float*)d_in[1];
  const float* beta1  = (const float*)d_in[2];
  const float* W_in   = (const float*)d_in[3];
  const float* conv_w = (const float*)d_in[4];
  const float* conv_b = (const float*)d_in[5];
  const float* W_xprj = (const float*)d_in[6];
  const float* W_dt   = (const float*)d_in[7];
  const float* b_dt   = (const float*)d_in[8];
  const float* A_log  = (const float*)d_in[9];
  const float* Dp     = (const float*)d_in[10];
  const float* W_out  = (const float*)d_in[11];
  const float* gamma2 = (const float*)d_in[12];
  const float* beta2  = (const float*)d_in[13];
  const float* W1     = (const float*)d_in[14];
  const float* b1     = (const float*)d_in[15];
  const float* W2     = (const float*)d_in[16];
  const float* b2     = (const float*)d_in[17];
  float* out = (float*)d_out;

  char* ws = (char*)d_ws;
  short* xnbf  = (short*)ws;                         // [0,8M): LN1 out; later xln
  short* xln   = xnbf;
  float* YU    = (float*)(ws + (8L << 20));          // [8M,72M): u slices f32; later dt_tr; later H+xmid
  float* dt_tr = YU;
  short* Hbuf  = (short*)(ws + (8L << 20));          // MLP hidden bf16 32MB
  float* xmid  = (float*)(ws + (40L << 20));         // 16MB
  float* ZT    = (float*)(ws + (72L << 20));         // [72M,136M): z_tr f32; later yo
  float* yo    = ZT;
  short* u_tr  = (short*)(ws + (136L << 20));        // [136M,168M): u_tr bf16; scan C overwrites with y
  float* xdbl  = (float*)(ws + (168L << 20));        // 4MB (2,NTOK,64) f32
  short* dtr   = (short*)(ws + (172L << 20));        // 1MB (2,NTOK,32) bf16
  float* hbuf  = (float*)(ws + (173L << 20));        // 16MB
  float* Sbuf  = (float*)(ws + (189L << 20));        // 1MB -> ends 190MB

  // 1. LN1 -> bf16
  ln1_kernel<<<NTOK / 4, 256, 0, stream>>>(x, gamma1, beta1, xnbf);
  // 2. in_proj both dirs: u -> YU (n,ch), z -> ZT (ch,n)
  gemm_bt<1, 0><<<dim3(128, 64, 1), 256, 0, stream>>>(xnbf, 0, W_in, 0, nullptr, 0,
                                                      YU, 0, nullptr, nullptr, ZT, C_, 4096);
  // 3. conv + silu -> u_tr (ch,n) bf16
  conv_silu_kernel<<<dim3(4, 16, 8), 256, 0, stream>>>(YU, conv_w, conv_b, u_tr);
  // 4. x_proj (A^T from u_tr): dtr bf16 + xdbl f32
  gemm_bt<5, 1><<<dim3(128, 1, 2), 256, 0, stream>>>(u_tr, SLICE, W_xprj, 64L * DI,
                                                     nullptr, 0, xdbl, 0, dtr, nullptr,
                                                     nullptr, DI, 64);
  // 5. dt_proj + softplus -> dt_tr (ch,n) f32 (over consumed u slices)
  gemm_bt<2, 0><<<dim3(128, 16, 2), 256, 0, stream>>>(dtr, (long)NTOK * 32, W_dt, (long)DI * 32,
                                                      b_dt, DI, dt_tr, 0, nullptr, nullptr,
                                                      nullptr, 32, DI);
  // 6-8. chunked scan: pass A (both dirs), combine, pass C (both dirs)
  scan_pass<0, 0><<<dim3(4, NC_, 4), 256, 0, stream>>>(dt_tr, u_tr, xdbl, ZT, A_log, Dp, hbuf, Sbuf, u_tr);
  scan_pass<0, 1><<<dim3(4, NC_, 4), 256, 0, stream>>>(dt_tr, u_tr, xdbl, ZT, A_log, Dp, hbuf, Sbuf, u_tr);
  scan_combine<<<32, 256, 0, stream>>>(A_log, hbuf, Sbuf);
  scan_pass<1, 0><<<dim3(4, NC_, 4), 256, 0, stream>>>(dt_tr, u_tr, xdbl, ZT, A_log, Dp, hbuf, Sbuf, u_tr);
  scan_pass<1, 1><<<dim3(4, NC_, 4), 256, 0, stream>>>(dt_tr, u_tr, xdbl, ZT, A_log, Dp, hbuf, Sbuf, u_tr);
  // 9. out_proj (A^T from y in u_tr) -> yo f32 (over consumed z_tr)
  gemm_bt<0, 1><<<dim3(128, 8, 2), 256, 0, stream>>>(u_tr, SLICE, W_out, (long)C_ * DI,
                                                     nullptr, 0, yo, (long)NTOK * C_,
                                                     nullptr, nullptr, nullptr, DI, C_);
  // 10. residual combine + LN2
  combine_ln2_kernel<<<NTOK / 4, 256, 0, stream>>>(x, yo, gamma2, beta2, xmid, xln);
  // 11. MLP up + gelu -> Hbuf bf16 (over consumed dt_tr)
  gemm_bt<3, 0><<<dim3(128, 32, 1), 256, 0, stream>>>(xln, 0, W1, 0, b1, 0,
                                                      nullptr, 0, Hbuf, nullptr, nullptr, C_, 2048);
  // 12. MLP down + bias + residual -> out f32
  gemm_bt<4, 0><<<dim3(128, 8, 1), 256, 0, stream>>>(Hbuf, 0, W2, 0, b2, 0,
                                                     out, 0, nullptr, xmid, nullptr, 2048, C_);
}

// Round 3
// 484.883 us; speedup vs baseline: 4.1528x; 1.3696x over previous
//
#include <hip/hip_runtime.h>
#include <math.h>

#define B_ 4
#define L_ 2048
#define C_ 512
#define DI 1024
#define DS 16
#define NTOK 8192
#define SLICE ((long)NTOK * DI)
#define T_ 64
#define NC_ 32

typedef __attribute__((ext_vector_type(4))) float  f32x4;
typedef __attribute__((ext_vector_type(4))) short  s16x4;
typedef __attribute__((ext_vector_type(8))) short  s16x8;
typedef __attribute__((ext_vector_type(8))) __bf16 bf16x8;

__device__ __forceinline__ float bf2f(short s) {
  return __uint_as_float(((unsigned)(unsigned short)s) << 16);
}
__device__ __forceinline__ short f2bf(float f) {
  unsigned u = __float_as_uint(f);
  u += 0x7fffu + ((u >> 16) & 1u);
  return (short)(u >> 16);
}
__device__ __forceinline__ f32x4 mfma16(s16x8 a, s16x8 b, f32x4 c) {
  return __builtin_amdgcn_mfma_f32_16x16x32_bf16(
      __builtin_bit_cast(bf16x8, a), __builtin_bit_cast(bf16x8, b), c, 0, 0, 0);
}

// ---------------- weight pre-cast f32 -> bf16 ----------------
__global__ __launch_bounds__(256) void castw_kernel(const float* __restrict__ s,
                                                    short* __restrict__ d, int n) {
  int i = (blockIdx.x * 256 + threadIdx.x) * 4;
  if (i >= n) return;
  f32x4 v = *(const f32x4*)(s + i);
  s16x4 o;
#pragma unroll
  for (int k = 0; k < 4; ++k) o[k] = f2bf(v[k]);
  *(s16x4*)(d + i) = o;
}

// ---------------- LayerNorm(x) -> bf16 (one wave per token) ----------------
__global__ __launch_bounds__(256) void ln1_kernel(
    const float* __restrict__ x, const float* __restrict__ g,
    const float* __restrict__ bt, short* __restrict__ out)
{
  int tok  = blockIdx.x * 4 + (threadIdx.x >> 6);
  int lane = threadIdx.x & 63;
  const float* row = x + (long)tok * C_ + lane * 8;
  f32x4 a0 = *(const f32x4*)row, a1 = *(const f32x4*)(row + 4);
  float s = 0.f, q = 0.f;
#pragma unroll
  for (int i = 0; i < 4; ++i) { s += a0[i] + a1[i]; q += a0[i]*a0[i] + a1[i]*a1[i]; }
#pragma unroll
  for (int o = 1; o < 64; o <<= 1) { s += __shfl_xor(s, o); q += __shfl_xor(q, o); }
  float mu = s * (1.f / C_);
  float rs = rsqrtf(q * (1.f / C_) - mu * mu + 1e-5f);
  f32x4 g0 = *(const f32x4*)(g + lane*8), g1 = *(const f32x4*)(g + lane*8 + 4);
  f32x4 b0 = *(const f32x4*)(bt + lane*8), b1 = *(const f32x4*)(bt + lane*8 + 4);
  s16x8 o8;
#pragma unroll
  for (int i = 0; i < 4; ++i) {
    o8[i]     = f2bf((a0[i] - mu) * rs * g0[i] + b0[i]);
    o8[4 + i] = f2bf((a1[i] - mu) * rs * g1[i] + b1[i]);
  }
  *(s16x8*)(out + (long)tok * C_ + lane * 8) = o8;
}

// ------- x_mid = x + 0.5*(y0+y1); LN2(x_mid) -> bf16; x_mid -> f32 -------
__global__ __launch_bounds__(256) void combine_ln2_kernel(
    const float* __restrict__ x, const float* __restrict__ yo,
    const float* __restrict__ g, const float* __restrict__ bt,
    float* __restrict__ xmid, short* __restrict__ xln)
{
  int tok  = blockIdx.x * 4 + (threadIdx.x >> 6);
  int lane = threadIdx.x & 63;
  long base = (long)tok * C_ + lane * 8;
  f32x4 a0 = *(const f32x4*)(x + base),  a1 = *(const f32x4*)(x + base + 4);
  f32x4 p0 = *(const f32x4*)(yo + base), p1 = *(const f32x4*)(yo + base + 4);
  f32x4 q0 = *(const f32x4*)(yo + (long)NTOK * C_ + base);
  f32x4 q1 = *(const f32x4*)(yo + (long)NTOK * C_ + base + 4);
  a0 = a0 + 0.5f * (p0 + q0);
  a1 = a1 + 0.5f * (p1 + q1);
  *(f32x4*)(xmid + base) = a0;
  *(f32x4*)(xmid + base + 4) = a1;
  float s = 0.f, q = 0.f;
#pragma unroll
  for (int i = 0; i < 4; ++i) { s += a0[i] + a1[i]; q += a0[i]*a0[i] + a1[i]*a1[i]; }
#pragma unroll
  for (int o = 1; o < 64; o <<= 1) { s += __shfl_xor(s, o); q += __shfl_xor(q, o); }
  float mu = s * (1.f / C_);
  float rs = rsqrtf(q * (1.f / C_) - mu * mu + 1e-5f);
  f32x4 g0 = *(const f32x4*)(g + lane*8), g1 = *(const f32x4*)(g + lane*8 + 4);
  f32x4 b0 = *(const f32x4*)(bt + lane*8), b1 = *(const f32x4*)(bt + lane*8 + 4);
  s16x8 o8;
#pragma unroll
  for (int i = 0; i < 4; ++i) {
    o8[i]     = f2bf((a0[i] - mu) * rs * g0[i] + b0[i]);
    o8[4 + i] = f2bf((a1[i] - mu) * rs * g1[i] + b1[i]);
  }
  *(s16x8*)(xln + (long)tok * C_ + lane * 8) = o8;
}

// ------- depthwise conv + bias + silu; (d,n,ch) bf16 -> (d,n,ch) bf16 -------
__global__ __launch_bounds__(256) void conv_silu_kernel(
    const short* __restrict__ ubuf, const float* __restrict__ cw,
    const float* __restrict__ cb, short* __restrict__ ucv)
{
  int ch = blockIdx.x * 256 + threadIdx.x;   // 0..1023
  int tc = blockIdx.y;                       // 0..15 (chunks of 128)
  int db = blockIdx.z;                       // d*4 + b
  int d = db >> 2, b = db & 3;
  const short* U = ubuf + ((long)d * NTOK + (long)b * L_) * DI + ch;
  short* O = ucv + ((long)d * NTOK + (long)b * L_) * DI + ch;
  f32x4 w4 = *(const f32x4*)(cw + ((long)d * DI + ch) * 4);
  float bias = cb[d * DI + ch];
  int t0 = tc * 128;
  if (d == 0) {
    float h3 = (t0 >= 3) ? bf2f(U[(long)(t0 - 3) * DI]) : 0.f;
    float h2 = (t0 >= 2) ? bf2f(U[(long)(t0 - 2) * DI]) : 0.f;
    float h1 = (t0 >= 1) ? bf2f(U[(long)(t0 - 1) * DI]) : 0.f;
    for (int t = t0; t < t0 + 128; ++t) {
      float cur = bf2f(U[(long)t * DI]);
      float v = w4[0]*h3 + w4[1]*h2 + w4[2]*h1 + w4[3]*cur + bias;
      v = v / (1.f + __builtin_amdgcn_exp2f(-1.4426950408889634f * v));
      O[(long)t * DI] = f2bf(v);
      h3 = h2; h2 = h1; h1 = cur;
    }
  } else {
    float a0v = bf2f(U[(long)t0 * DI]);
    float a1v = (t0 + 1 < L_) ? bf2f(U[(long)(t0 + 1) * DI]) : 0.f;
    float a2v = (t0 + 2 < L_) ? bf2f(U[(long)(t0 + 2) * DI]) : 0.f;
    for (int t = t0; t < t0 + 128; ++t) {
      float a3v = (t + 3 < L_) ? bf2f(U[(long)(t + 3) * DI]) : 0.f;
      float v = w4[3]*a0v + w4[2]*a1v + w4[1]*a2v + w4[0]*a3v + bias;
      v = v / (1.f + __builtin_amdgcn_exp2f(-1.4426950408889634f * v));
      O[(long)t * DI] = f2bf(v);
      a0v = a1v; a1v = a2v; a2v = a3v;
    }
  }
}

// ---------------- selective scan, 2-pass chunked, (n,ch) layout ----------------
template <int PASS, int DIR>
__global__ __launch_bounds__(256) void scan_pass(
    const short* __restrict__ dtb, const short* __restrict__ ucv,
    const float* __restrict__ xdbl, const short* __restrict__ zbuf,
    const float* __restrict__ Alog, const float* __restrict__ Dp,
    float* __restrict__ hbuf, float* __restrict__ Sbuf, short* __restrict__ ybuf)
{
  __shared__ float sBC[T_ * 32];
  const int tid = threadIdx.x;
  const int ch  = blockIdx.x * 256 + tid;
  const int c   = blockIdx.y;
  const int b   = blockIdx.z;
  const int db  = DIR * 4 + b;
  const long n0 = (long)b * L_ + (long)c * T_;
  const float* xrow = xdbl + ((long)DIR * NTOK + n0) * 64 + 32;
  if (PASS == 0) {  // B only: [T_][16]
    int r = tid >> 2, cc4 = (tid & 3) * 4;
    *(f32x4*)&sBC[r * 16 + cc4] = *(const f32x4*)(xrow + (long)r * 64 + cc4);
  } else {          // B|C: [T_][32]
    int r = tid >> 2, cc8 = (tid & 3) * 8;
    *(f32x4*)&sBC[r * 32 + cc8]     = *(const f32x4*)(xrow + (long)r * 64 + cc8);
    *(f32x4*)&sBC[r * 32 + cc8 + 4] = *(const f32x4*)(xrow + (long)r * 64 + cc8 + 4);
  }
  __syncthreads();
  float A2[16];
  {
    const float* Ap = Alog + ((long)DIR * DI + ch) * DS;
#pragma unroll
    for (int s = 0; s < 16; ++s) A2[s] = -expf(Ap[s]) * 1.4426950408889634f;
  }
  const long base = ((long)DIR * NTOK + n0) * DI + ch;
  const short* dtp = dtb + base;
  const short* up  = ucv + base;
  const short* zp  = zbuf + base;
  short* yp = ybuf + base;
  const long hb = (((long)db * NC_ + c) * DI + ch) * 16;
  float h[16];
  float Dv = 0.f;
  if (PASS == 1) {
#pragma unroll
    for (int s = 0; s < 16; s += 4) *(f32x4*)&h[s] = *(const f32x4*)&hbuf[hb + s];
    Dv = Dp[DIR * DI + ch];
  } else {
#pragma unroll
    for (int s = 0; s < 16; ++s) h[s] = 0.f;
  }
  float S = 0.f;
#pragma unroll
  for (int ib = 0; ib < T_ / 8; ++ib) {
    const int t0 = DIR ? (T_ - 8 - ib * 8) : ib * 8;
    float dt8[8], u8[8], z8[8];
#pragma unroll
    for (int j = 0; j < 8; ++j) {
      long o = (long)(t0 + j) * DI;
      dt8[j] = bf2f(dtp[o]);
      u8[j]  = bf2f(up[o]);
      if (PASS == 1) z8[j] = bf2f(zp[o]);
    }
    short y8[8];
#pragma unroll
    for (int jj = 0; jj < 8; ++jj) {
      const int j = DIR ? (7 - jj) : jj;
      float dtv = dt8[j], uv = u8[j];
      float wv = dtv * uv;
      const float* bc = &sBC[(t0 + j) * (PASS ? 32 : 16)];
      float p = 0.f;
#pragma unroll
      for (int s = 0; s < 16; ++s) {
        float e = __builtin_amdgcn_exp2f(dtv * A2[s]);
        h[s] = e * h[s] + wv * bc[s];
        if (PASS == 1) p += h[s] * bc[16 + s];
      }
      if (PASS == 0) {
        S += dtv;
      } else {
        float z = z8[j];
        float sig = 1.f / (1.f + __builtin_amdgcn_exp2f(-1.4426950408889634f * z));
        y8[j] = f2bf((p + uv * Dv) * (z * sig));
      }
    }
    if (PASS == 1) {
#pragma unroll
      for (int j = 0; j < 8; ++j) yp[(long)(t0 + j) * DI] = y8[j];
    }
  }
  if (PASS == 0) {
#pragma unroll
    for (int s = 0; s < 16; s += 4) *(f32x4*)&hbuf[hb + s] = *(const f32x4*)&h[s];
    Sbuf[((long)db * NC_ + c) * DI + ch] = S;
  }
}

// ---------------- chunk combine: hbuf hend -> hin ----------------
__global__ __launch_bounds__(256) void scan_combine(
    const float* __restrict__ Alog, float* __restrict__ hbuf,
    const float* __restrict__ Sbuf)
{
  int tid = threadIdx.x;
  int ch = (blockIdx.x & 3) * 256 + tid;
  int db = blockIdx.x >> 2;     // 0..7
  int d = db >> 2;
  float A2[16];
  const float* Ap = Alog + ((long)d * DI + ch) * DS;
#pragma unroll
  for (int s = 0; s < 16; ++s) A2[s] = -expf(Ap[s]) * 1.4426950408889634f;
  float h[16];
#pragma unroll
  for (int s = 0; s < 16; ++s) h[s] = 0.f;
  for (int cc = 0; cc < NC_; ++cc) {
    int c = (d == 1) ? (NC_ - 1 - cc) : cc;
    long hb = (((long)db * NC_ + c) * DI + ch) * 16;
    float S = Sbuf[((long)db * NC_ + c) * DI + ch];
    float he[16];
#pragma unroll
    for (int s = 0; s < 16; s += 4) *(f32x4*)&he[s] = *(const f32x4*)&hbuf[hb + s];
#pragma unroll
    for (int s = 0; s < 16; s += 4) *(f32x4*)&hbuf[hb + s] = *(const f32x4*)&h[s];
#pragma unroll
    for (int s = 0; s < 16; ++s) h[s] = __builtin_amdgcn_exp2f(A2[s] * S) * h[s] + he[s];
  }
}

// ---------------- m97-style MFMA GEMM: C = A(bf16) @ W(bf16).T ----------------
// 128xBN tile, BK=32, global_load_lds(16B), both-sides XOR swizzle kg^=(row>>1)&3.
// EPI: 0 f32 out; 1 in_proj split (u/z bf16); 2 +bias softplus -> bf16;
//      3 +bias gelu -> bf16; 4 +bias +res -> f32; 5 x_proj split (dtr bf16 + xdbl f32)
template <int EPI, int BN>
__global__ __launch_bounds__(256) void gemm_m97(
    const short* __restrict__ X, long sX,
    const short* __restrict__ Wb, long sW,
    const float* __restrict__ bias, long sBias,
    float* __restrict__ outF, long sOutF,
    short* __restrict__ outB,
    const float* __restrict__ res,
    short* __restrict__ outB2,
    int K, int N)
{
  constexpr int MI = (BN == 128) ? 4 : 2;
  __shared__ short sA[128 * 32];
  __shared__ short sB[BN * 32];
  const int tid  = threadIdx.x;
  const int lane = tid & 63;
  const int w    = tid >> 6;
  const int wm   = (BN == 128) ? (w >> 1) : w;
  const int wn   = (BN == 128) ? (w & 1) : 0;
  const int d    = blockIdx.z;
  const int m0   = blockIdx.x * 128;
  const int n0   = blockIdx.y * BN;
  const short* Xp = X + (long)d * sX + (long)m0 * K;
  const short* Wp = Wb + (long)d * sW + (long)n0 * K;

  f32x4 acc[MI][4];
#pragma unroll
  for (int i = 0; i < MI; ++i)
#pragma unroll
    for (int j = 0; j < 4; ++j) acc[i][j] = (f32x4){0.f, 0.f, 0.f, 0.f};

  const int lrow = lane >> 2;   // row within 16-row wave chunk
  const int lkg  = lane & 3;

  for (int k0 = 0; k0 < K; k0 += 32) {
#pragma unroll
    for (int j = 0; j < 2; ++j) {          // A tile: 128 rows
      int row = w * 16 + j * 64 + lrow;
      int kgs = lkg ^ ((row >> 1) & 3);
      __builtin_amdgcn_global_load_lds(
        (const __attribute__((address_space(1))) unsigned*)(Xp + (long)row * K + k0 + kgs * 8),
        (__attribute__((address_space(3))) unsigned*)(sA + (w * 16 + j * 64) * 32),
        16, 0, 0);
    }
#pragma unroll
    for (int j = 0; j < BN / 64; ++j) {    // B tile: BN rows
      int row = w * 16 + j * 64 + lrow;
      int kgs = lkg ^ ((row >> 1) & 3);
      __builtin_amdgcn_global_load_lds(
        (const __attribute__((address_space(1))) unsigned*)(Wp + (long)row * K + k0 + kgs * 8),
        (__attribute__((address_space(3))) unsigned*)(sB + (w * 16 + j * 64) * 32),
        16, 0, 0);
    }
    __syncthreads();
    s16x8 af[MI], bfr[4];
#pragma unroll
    for (int mi = 0; mi < MI; ++mi) {
      int row = wm * (MI * 16) + mi * 16 + (lane & 15);
      int kg = (lane >> 4) ^ ((row >> 1) & 3);
      af[mi] = *(const s16x8*)((const char*)sA + row * 64 + kg * 16);
    }
#pragma unroll
    for (int ni = 0; ni < 4; ++ni) {
      int row = wn * 64 + ni * 16 + (lane & 15);
      int kg = (lane >> 4) ^ ((row >> 1) & 3);
      bfr[ni] = *(const s16x8*)((const char*)sB + row * 64 + kg * 16);
    }
#pragma unroll
    for (int mi = 0; mi < MI; ++mi)
#pragma unroll
      for (int ni = 0; ni < 4; ++ni)
        acc[mi][ni] = mfma16(af[mi], bfr[ni], acc[mi][ni]);
    __syncthreads();
  }

  const int col0 = lane & 15;
  const int rsub = (lane >> 4) * 4;
#pragma unroll
  for (int mi = 0; mi < MI; ++mi) {
    int row = m0 + wm * (MI * 16) + mi * 16 + rsub;
#pragma unroll
    for (int ni = 0; ni < 4; ++ni) {
      int col = n0 + wn * 64 + ni * 16 + col0;
#pragma unroll
      for (int j = 0; j < 4; ++j) {
        float v = acc[mi][ni][j];
        int r = row + j;
        if constexpr (EPI == 0) {
          outF[(long)d * sOutF + (long)r * N + col] = v;
        } else if constexpr (EPI == 1) {
          int d2 = col >> 11, cc = col & 2047;
          long o = ((long)d2 * NTOK + r) * DI;
          if (cc < DI) outB[o + cc] = f2bf(v);
          else         outB2[o + cc - DI] = f2bf(v);
        } else if constexpr (EPI == 2) {
          float t = v + bias[(long)d * sBias + col];
          t = (t > 20.f) ? t : log1pf(expf(t));
          outB[((long)d * NTOK + r) * DI + col] = f2bf(t);
        } else if constexpr (EPI == 3) {
          float t = v + bias[col];
          t = 0.5f * t * (1.f + erff(t * 0.70710678118654752f));
          outB[(long)r * N + col] = f2bf(t);
        } else if constexpr (EPI == 4) {
          outF[(long)r * N + col] = v + bias[col] + res[(long)r * N + col];
        } else if constexpr (EPI == 5) {
          if (col < 32) outB[((long)d * NTOK + r) * 32 + col] = f2bf(v);
          else          outF[((long)d * NTOK + r) * 64 + col] = v;
        }
      }
    }
  }
}

extern "C" void kernel_launch(void* const* d_in, const int* in_sizes, int n_in,
                              void* d_out, int out_size, void* d_ws, size_t ws_size,
                              hipStream_t stream) {
  const float* x      = (const float*)d_in[0];
  const float* gamma1 = (const float*)d_in[1];
  const float* beta1  = (const float*)d_in[2];
  const float* W_in   = (const float*)d_in[3];
  const float* conv_w = (const float*)d_in[4];
  const float* conv_b = (const float*)d_in[5];
  const float* W_xprj = (const float*)d_in[6];
  const float* W_dt   = (const float*)d_in[7];
  const float* b_dt   = (const float*)d_in[8];
  const float* A_log  = (const float*)d_in[9];
  const float* Dp     = (const float*)d_in[10];
  const float* W_out  = (const float*)d_in[11];
  const float* gamma2 = (const float*)d_in[12];
  const float* beta2  = (const float*)d_in[13];
  const float* W1     = (const float*)d_in[14];
  const float* b1     = (const float*)d_in[15];
  const float* W2     = (const float*)d_in[16];
  const float* b2     = (const float*)d_in[17];
  float* out = (float*)d_out;

  char* ws = (char*)d_ws;
  short* wb_in  = (short*)(ws);                              // 4 MB
  short* wb_xp  = (short*)(ws + (4L << 20));                 // 256 KB
  short* wb_dt  = (short*)(ws + (4L << 20) + (256L << 10));  // 128 KB
  short* wb_out = (short*)(ws + (4L << 20) + (384L << 10));  // 2 MB
  short* wb_w1  = (short*)(ws + (6L << 20) + (384L << 10));  // 2 MB
  short* wb_w2  = (short*)(ws + (8L << 20) + (384L << 10));  // 2 MB
  short* xnbf = (short*)(ws + (12L << 20));   // 8 MB; later xln
  short* ubuf = (short*)(ws + (20L << 20));   // 32 MB (d,n,ch) raw u
  short* zbuf = (short*)(ws + (52L << 20));   // 32 MB; later yo f32
  short* ucv  = (short*)(ws + (84L << 20));   // 32 MB conv-out; y in-place
  short* dtb  = (short*)(ws + (116L << 20));  // 32 MB; later Hbuf
  float* xdbl = (float*)(ws + (148L << 20));  // 4 MB
  short* dtr  = (short*)(ws + (152L << 20));  // 1 MB
  float* hbuf = (float*)(ws + (153L << 20));  // 16 MB
  float* Sbuf = (float*)(ws + (169L << 20));  // 1 MB
  float* xmid = (float*)(ws + (170L << 20));  // 16 MB -> ends 186 MB
  float* yo   = (float*)zbuf;
  short* xln  = xnbf;
  short* Hbuf = dtb;

  // 0. pre-cast weights to bf16
  castw_kernel<<<2048, 256, 0, stream>>>(W_in,   wb_in,  2097152);
  castw_kernel<<<128,  256, 0, stream>>>(W_xprj, wb_xp,  131072);
  castw_kernel<<<64,   256, 0, stream>>>(W_dt,   wb_dt,  65536);
  castw_kernel<<<1024, 256, 0, stream>>>(W_out,  wb_out, 1048576);
  castw_kernel<<<1024, 256, 0, stream>>>(W1,     wb_w1,  1048576);
  castw_kernel<<<1024, 256, 0, stream>>>(W2,     wb_w2,  1048576);
  // 1. LN1 -> bf16
  ln1_kernel<<<NTOK / 4, 256, 0, stream>>>(x, gamma1, beta1, xnbf);
  // 2. in_proj both dirs: u -> ubuf, z -> zbuf (both (d,n,ch) bf16)
  gemm_m97<1, 128><<<dim3(64, 32, 1), 256, 0, stream>>>(
      xnbf, 0, wb_in, 0, nullptr, 0, nullptr, 0, ubuf, nullptr, zbuf, C_, 4096);
  // 3. conv + silu -> ucv
  conv_silu_kernel<<<dim3(4, 16, 8), 256, 0, stream>>>(ubuf, conv_w, conv_b, ucv);
  // 4. x_proj: dtr bf16 + xdbl f32
  gemm_m97<5, 64><<<dim3(64, 1, 2), 256, 0, stream>>>(
      ucv, SLICE, wb_xp, 64L * DI, nullptr, 0, xdbl, 0, dtr, nullptr, nullptr, DI, 64);
  // 5. dt_proj + softplus -> dtb bf16
  gemm_m97<2, 128><<<dim3(64, 8, 2), 256, 0, stream>>>(
      dtr, (long)NTOK * 32, wb_dt, (long)DI * 32, b_dt, DI, nullptr, 0, dtb, nullptr,
      nullptr, 32, DI);
  // 6-8. chunked scan
  scan_pass<0, 0><<<dim3(4, NC_, 4), 256, 0, stream>>>(dtb, ucv, xdbl, zbuf, A_log, Dp, hbuf, Sbuf, ucv);
  scan_pass<0, 1><<<dim3(4, NC_, 4), 256, 0, stream>>>(dtb, ucv, xdbl, zbuf, A_log, Dp, hbuf, Sbuf, ucv);
  scan_combine<<<32, 256, 0, stream>>>(A_log, hbuf, Sbuf);
  scan_pass<1, 0><<<dim3(4, NC_, 4), 256, 0, stream>>>(dtb, ucv, xdbl, zbuf, A_log, Dp, hbuf, Sbuf, ucv);
  scan_pass<1, 1><<<dim3(4, NC_, 4), 256, 0, stream>>>(dtb, ucv, xdbl, zbuf, A_log, Dp, hbuf, Sbuf, ucv);
  // 9. out_proj -> yo f32 (over consumed zbuf)
  gemm_m97<0, 128><<<dim3(64, 4, 2), 256, 0, stream>>>(
      ucv, SLICE, wb_out, (long)C_ * DI, nullptr, 0, yo, (long)NTOK * C_, nullptr,
      nullptr, nullptr, DI, C_);
  // 10. residual combine + LN2
  combine_ln2_kernel<<<NTOK / 4, 256, 0, stream>>>(x, yo, gamma2, beta2, xmid, xln);
  // 11. MLP up + gelu -> Hbuf bf16
  gemm_m97<3, 128><<<dim3(64, 16, 1), 256, 0, stream>>>(
      xln, 0, wb_w1, 0, b1, 0, nullptr, 0, Hbuf, nullptr, nullptr, C_, 2048);
  // 12. MLP down + bias + residual -> out f32
  gemm_m97<4, 128><<<dim3(64, 4, 1), 256, 0, stream>>>(
      Hbuf, 0, wb_w2, 0, b2, 0, out, 0, nullptr, xmid, nullptr, 2048, C_);
}

// Round 4
// 419.483 us; speedup vs baseline: 4.8003x; 1.1559x over previous
//
#include <hip/hip_runtime.h>
#include <math.h>

#define B_ 4
#define L_ 2048
#define C_ 512
#define DI 1024
#define DS 16
#define NTOK 8192
#define SLICE ((long)NTOK * DI)
#define T_ 64
#define NC_ 32
#define SDT_LD 264

typedef __attribute__((ext_vector_type(4))) float  f32x4;
typedef __attribute__((ext_vector_type(4))) short  s16x4;
typedef __attribute__((ext_vector_type(8))) short  s16x8;
typedef __attribute__((ext_vector_type(8))) __bf16 bf16x8;

#define LOG2E 1.4426950408889634f
#define LN2   0.69314718055994531f

__device__ __forceinline__ float bf2f(short s) {
  return __uint_as_float(((unsigned)(unsigned short)s) << 16);
}
__device__ __forceinline__ short f2bf(float f) {
  unsigned u = __float_as_uint(f);
  u += 0x7fffu + ((u >> 16) & 1u);
  return (short)(u >> 16);
}
__device__ __forceinline__ f32x4 mfma16(s16x8 a, s16x8 b, f32x4 c) {
  return __builtin_amdgcn_mfma_f32_16x16x32_bf16(
      __builtin_bit_cast(bf16x8, a), __builtin_bit_cast(bf16x8, b), c, 0, 0, 0);
}
__device__ __forceinline__ float fast_sigmoid(float z) {
  return __builtin_amdgcn_rcpf(1.f + __builtin_amdgcn_exp2f(-LOG2E * z));
}
__device__ __forceinline__ float fast_softplus(float t) {
  return (t > 15.f) ? t
    : LN2 * __builtin_amdgcn_logf(1.f + __builtin_amdgcn_exp2f(LOG2E * t));
}

// ---------------- weight pre-cast f32 -> bf16 ----------------
__global__ __launch_bounds__(256) void castw_kernel(const float* __restrict__ s,
                                                    short* __restrict__ d, int n) {
  int i = (blockIdx.x * 256 + threadIdx.x) * 4;
  if (i >= n) return;
  f32x4 v = *(const f32x4*)(s + i);
  s16x4 o;
#pragma unroll
  for (int k = 0; k < 4; ++k) o[k] = f2bf(v[k]);
  *(s16x4*)(d + i) = o;
}

// ---------------- LayerNorm(x) -> bf16 (one wave per token) ----------------
__global__ __launch_bounds__(256) void ln1_kernel(
    const float* __restrict__ x, const float* __restrict__ g,
    const float* __restrict__ bt, short* __restrict__ out)
{
  int tok  = blockIdx.x * 4 + (threadIdx.x >> 6);
  int lane = threadIdx.x & 63;
  const float* row = x + (long)tok * C_ + lane * 8;
  f32x4 a0 = *(const f32x4*)row, a1 = *(const f32x4*)(row + 4);
  float s = 0.f, q = 0.f;
#pragma unroll
  for (int i = 0; i < 4; ++i) { s += a0[i] + a1[i]; q += a0[i]*a0[i] + a1[i]*a1[i]; }
#pragma unroll
  for (int o = 1; o < 64; o <<= 1) { s += __shfl_xor(s, o); q += __shfl_xor(q, o); }
  float mu = s * (1.f / C_);
  float rs = rsqrtf(q * (1.f / C_) - mu * mu + 1e-5f);
  f32x4 g0 = *(const f32x4*)(g + lane*8), g1 = *(const f32x4*)(g + lane*8 + 4);
  f32x4 b0 = *(const f32x4*)(bt + lane*8), b1 = *(const f32x4*)(bt + lane*8 + 4);
  s16x8 o8;
#pragma unroll
  for (int i = 0; i < 4; ++i) {
    o8[i]     = f2bf((a0[i] - mu) * rs * g0[i] + b0[i]);
    o8[4 + i] = f2bf((a1[i] - mu) * rs * g1[i] + b1[i]);
  }
  *(s16x8*)(out + (long)tok * C_ + lane * 8) = o8;
}

// ------- x_mid = x + 0.5*(y0+y1); LN2(x_mid) -> bf16; x_mid -> f32 -------
__global__ __launch_bounds__(256) void combine_ln2_kernel(
    const float* __restrict__ x, const float* __restrict__ yo,
    const float* __restrict__ g, const float* __restrict__ bt,
    float* __restrict__ xmid, short* __restrict__ xln)
{
  int tok  = blockIdx.x * 4 + (threadIdx.x >> 6);
  int lane = threadIdx.x & 63;
  long base = (long)tok * C_ + lane * 8;
  f32x4 a0 = *(const f32x4*)(x + base),  a1 = *(const f32x4*)(x + base + 4);
  f32x4 p0 = *(const f32x4*)(yo + base), p1 = *(const f32x4*)(yo + base + 4);
  f32x4 q0 = *(const f32x4*)(yo + (long)NTOK * C_ + base);
  f32x4 q1 = *(const f32x4*)(yo + (long)NTOK * C_ + base + 4);
  a0 = a0 + 0.5f * (p0 + q0);
  a1 = a1 + 0.5f * (p1 + q1);
  *(f32x4*)(xmid + base) = a0;
  *(f32x4*)(xmid + base + 4) = a1;
  float s = 0.f, q = 0.f;
#pragma unroll
  for (int i = 0; i < 4; ++i) { s += a0[i] + a1[i]; q += a0[i]*a0[i] + a1[i]*a1[i]; }
#pragma unroll
  for (int o = 1; o < 64; o <<= 1) { s += __shfl_xor(s, o); q += __shfl_xor(q, o); }
  float mu = s * (1.f / C_);
  float rs = rsqrtf(q * (1.f / C_) - mu * mu + 1e-5f);
  f32x4 g0 = *(const f32x4*)(g + lane*8), g1 = *(const f32x4*)(g + lane*8 + 4);
  f32x4 b0 = *(const f32x4*)(bt + lane*8), b1 = *(const f32x4*)(bt + lane*8 + 4);
  s16x8 o8;
#pragma unroll
  for (int i = 0; i < 4; ++i) {
    o8[i]     = f2bf((a0[i] - mu) * rs * g0[i] + b0[i]);
    o8[4 + i] = f2bf((a1[i] - mu) * rs * g1[i] + b1[i]);
  }
  *(s16x8*)(xln + (long)tok * C_ + lane * 8) = o8;
}

// ------- depthwise conv + bias + silu; (d,n,ch) bf16 -> (d,n,ch) bf16 -------
__global__ __launch_bounds__(256) void conv_silu_kernel(
    const short* __restrict__ ubuf, const float* __restrict__ cw,
    const float* __restrict__ cb, short* __restrict__ ucv)
{
  int ch = blockIdx.x * 256 + threadIdx.x;   // 0..1023
  int tc = blockIdx.y;                       // 0..15 (chunks of 128)
  int db = blockIdx.z;                       // d*4 + b
  int d = db >> 2, b = db & 3;
  const short* U = ubuf + ((long)d * NTOK + (long)b * L_) * DI + ch;
  short* O = ucv + ((long)d * NTOK + (long)b * L_) * DI + ch;
  f32x4 w4 = *(const f32x4*)(cw + ((long)d * DI + ch) * 4);
  float bias = cb[d * DI + ch];
  int t0 = tc * 128;
  if (d == 0) {
    float h3 = (t0 >= 3) ? bf2f(U[(long)(t0 - 3) * DI]) : 0.f;
    float h2 = (t0 >= 2) ? bf2f(U[(long)(t0 - 2) * DI]) : 0.f;
    float h1 = (t0 >= 1) ? bf2f(U[(long)(t0 - 1) * DI]) : 0.f;
    for (int t = t0; t < t0 + 128; ++t) {
      float cur = bf2f(U[(long)t * DI]);
      float v = w4[0]*h3 + w4[1]*h2 + w4[2]*h1 + w4[3]*cur + bias;
      v = v * fast_sigmoid(v);
      O[(long)t * DI] = f2bf(v);
      h3 = h2; h2 = h1; h1 = cur;
    }
  } else {
    float a0v = bf2f(U[(long)t0 * DI]);
    float a1v = (t0 + 1 < L_) ? bf2f(U[(long)(t0 + 1) * DI]) : 0.f;
    float a2v = (t0 + 2 < L_) ? bf2f(U[(long)(t0 + 2) * DI]) : 0.f;
    for (int t = t0; t < t0 + 128; ++t) {
      float a3v = (t + 3 < L_) ? bf2f(U[(long)(t + 3) * DI]) : 0.f;
      float v = w4[3]*a0v + w4[2]*a1v + w4[1]*a2v + w4[0]*a3v + bias;
      v = v * fast_sigmoid(v);
      O[(long)t * DI] = f2bf(v);
      a0v = a1v; a1v = a2v; a2v = a3v;
    }
  }
}

// ---------------- selective scan, 2-pass chunked, dt fused via MFMA ----------------
// dt[64 tok x 256 ch] = dtr(64x32) @ W_dt(256x32)^T + b_dt, softplus, staged in LDS.
template <int PASS, int DIR>
__global__ __launch_bounds__(256) void scan_pass(
    const short* __restrict__ dtr, const short* __restrict__ wdt,
    const float* __restrict__ bdt,
    const short* __restrict__ ucv, const float* __restrict__ xdbl,
    const short* __restrict__ zbuf,
    const float* __restrict__ Alog, const float* __restrict__ Dp,
    float* __restrict__ hbuf, float* __restrict__ Sbuf, short* __restrict__ ybuf)
{
  __shared__ float sBC[T_ * 32];
  __shared__ short sdt[T_ * SDT_LD];
  const int tid  = threadIdx.x;
  const int lane = tid & 63;
  const int w    = tid >> 6;
  const int ch   = blockIdx.x * 256 + tid;
  const int c    = blockIdx.y;
  const int b    = blockIdx.z;
  const int db   = DIR * 4 + b;
  const long n0  = (long)b * L_ + (long)c * T_;
  // stage B (and C for pass1) rows for this chunk
  const float* xrow = xdbl + ((long)DIR * NTOK + n0) * 64 + 32;
  if (PASS == 0) {
    int r = tid >> 2, cc4 = (tid & 3) * 4;
    *(f32x4*)&sBC[r * 16 + cc4] = *(const f32x4*)(xrow + (long)r * 64 + cc4);
  } else {
    int r = tid >> 2, cc8 = (tid & 3) * 8;
    *(f32x4*)&sBC[r * 32 + cc8]     = *(const f32x4*)(xrow + (long)r * 64 + cc8);
    *(f32x4*)&sBC[r * 32 + cc8 + 4] = *(const f32x4*)(xrow + (long)r * 64 + cc8 + 4);
  }
  // dt mini-GEMM: one MFMA K-step, operands direct from global
  {
    const short* dtrp = dtr + ((long)DIR * NTOK + n0) * 32;
    const short* wp   = wdt + ((long)DIR * DI + blockIdx.x * 256) * 32;
    s16x8 af[4], bfr[4];
#pragma unroll
    for (int mi = 0; mi < 4; ++mi)
      af[mi] = *(const s16x8*)(dtrp + (mi * 16 + (lane & 15)) * 32 + (lane >> 4) * 8);
#pragma unroll
    for (int ni = 0; ni < 4; ++ni)
      bfr[ni] = *(const s16x8*)(wp + (w * 64 + ni * 16 + (lane & 15)) * 32 + (lane >> 4) * 8);
    float bv[4];
#pragma unroll
    for (int ni = 0; ni < 4; ++ni)
      bv[ni] = bdt[DIR * DI + blockIdx.x * 256 + w * 64 + ni * 16 + (lane & 15)];
#pragma unroll
    for (int mi = 0; mi < 4; ++mi) {
#pragma unroll
      for (int ni = 0; ni < 4; ++ni) {
        f32x4 acc = {0.f, 0.f, 0.f, 0.f};
        acc = mfma16(af[mi], bfr[ni], acc);
#pragma unroll
        for (int j = 0; j < 4; ++j) {
          float sp = fast_softplus(acc[j] + bv[ni]);
          sdt[(mi * 16 + (lane >> 4) * 4 + j) * SDT_LD + w * 64 + ni * 16 + (lane & 15)]
            = f2bf(sp);
        }
      }
    }
  }
  __syncthreads();
  float A2[16];
  {
    const float* Ap = Alog + ((long)DIR * DI + ch) * DS;
#pragma unroll
    for (int s = 0; s < 16; ++s) A2[s] = -expf(Ap[s]) * LOG2E;
  }
  const long base = ((long)DIR * NTOK + n0) * DI + ch;
  const short* up  = ucv + base;
  const short* zp  = zbuf + base;
  short* yp = ybuf + base;
  const long hb = (((long)db * NC_ + c) * DI + ch) * 16;
  float h[16];
  float Dv = 0.f;
  if (PASS == 1) {
#pragma unroll
    for (int s = 0; s < 16; s += 4) *(f32x4*)&h[s] = *(const f32x4*)&hbuf[hb + s];
    Dv = Dp[DIR * DI + ch];
  } else {
#pragma unroll
    for (int s = 0; s < 16; ++s) h[s] = 0.f;
  }
  float S = 0.f;
#pragma unroll
  for (int ib = 0; ib < T_ / 8; ++ib) {
    const int t0 = DIR ? (T_ - 8 - ib * 8) : ib * 8;
    float u8[8], z8[8];
#pragma unroll
    for (int j = 0; j < 8; ++j) {
      long o = (long)(t0 + j) * DI;
      u8[j] = bf2f(up[o]);
      if (PASS == 1) z8[j] = bf2f(zp[o]);
    }
    short y8[8];
#pragma unroll
    for (int jj = 0; jj < 8; ++jj) {
      const int j = DIR ? (7 - jj) : jj;
      float dtv = bf2f(sdt[(t0 + j) * SDT_LD + tid]);
      float uv  = u8[j];
      float wv = dtv * uv;
      const float* bc = &sBC[(t0 + j) * (PASS ? 32 : 16)];
      float p = 0.f;
#pragma unroll
      for (int s = 0; s < 16; ++s) {
        float e = __builtin_amdgcn_exp2f(dtv * A2[s]);
        h[s] = e * h[s] + wv * bc[s];
        if (PASS == 1) p += h[s] * bc[16 + s];
      }
      if (PASS == 0) {
        S += dtv;
      } else {
        float z = z8[j];
        y8[j] = f2bf((p + uv * Dv) * (z * fast_sigmoid(z)));
      }
    }
    if (PASS == 1) {
#pragma unroll
      for (int j = 0; j < 8; ++j) yp[(long)(t0 + j) * DI] = y8[j];
    }
  }
  if (PASS == 0) {
#pragma unroll
    for (int s = 0; s < 16; s += 4) *(f32x4*)&hbuf[hb + s] = *(const f32x4*)&h[s];
    Sbuf[((long)db * NC_ + c) * DI + ch] = S;
  }
}

// ---------------- chunk combine: hbuf hend -> hin ----------------
__global__ __launch_bounds__(256) void scan_combine(
    const float* __restrict__ Alog, float* __restrict__ hbuf,
    const float* __restrict__ Sbuf)
{
  int tid = threadIdx.x;
  int ch = (blockIdx.x & 3) * 256 + tid;
  int db = blockIdx.x >> 2;     // 0..7
  int d = db >> 2;
  float A2[16];
  const float* Ap = Alog + ((long)d * DI + ch) * DS;
#pragma unroll
  for (int s = 0; s < 16; ++s) A2[s] = -expf(Ap[s]) * LOG2E;
  float h[16];
#pragma unroll
  for (int s = 0; s < 16; ++s) h[s] = 0.f;
  for (int cc = 0; cc < NC_; ++cc) {
    int c = (d == 1) ? (NC_ - 1 - cc) : cc;
    long hb = (((long)db * NC_ + c) * DI + ch) * 16;
    float S = Sbuf[((long)db * NC_ + c) * DI + ch];
    float he[16];
#pragma unroll
    for (int s = 0; s < 16; s += 4) *(f32x4*)&he[s] = *(const f32x4*)&hbuf[hb + s];
#pragma unroll
    for (int s = 0; s < 16; s += 4) *(f32x4*)&hbuf[hb + s] = *(const f32x4*)&h[s];
#pragma unroll
    for (int s = 0; s < 16; ++s) h[s] = __builtin_amdgcn_exp2f(A2[s] * S) * h[s] + he[s];
  }
}

// ---------------- m97-style MFMA GEMM: C = A(bf16) @ W(bf16).T ----------------
// EPI: 0 f32 out; 1 in_proj split (u/z bf16); 3 +bias gelu -> bf16;
//      4 +bias +res -> f32; 5 x_proj split (dtr bf16 + xdbl f32)
template <int EPI, int BN>
__global__ __launch_bounds__(256) void gemm_m97(
    const short* __restrict__ X, long sX,
    const short* __restrict__ Wb, long sW,
    const float* __restrict__ bias, long sBias,
    float* __restrict__ outF, long sOutF,
    short* __restrict__ outB,
    const float* __restrict__ res,
    short* __restrict__ outB2,
    int K, int N)
{
  constexpr int MI = (BN == 128) ? 4 : 2;
  __shared__ short sA[128 * 32];
  __shared__ short sB[BN * 32];
  const int tid  = threadIdx.x;
  const int lane = tid & 63;
  const int w    = tid >> 6;
  const int wm   = (BN == 128) ? (w >> 1) : w;
  const int wn   = (BN == 128) ? (w & 1) : 0;
  const int d    = blockIdx.z;
  const int m0   = blockIdx.x * 128;
  const int n0   = blockIdx.y * BN;
  const short* Xp = X + (long)d * sX + (long)m0 * K;
  const short* Wp = Wb + (long)d * sW + (long)n0 * K;

  f32x4 acc[MI][4];
#pragma unroll
  for (int i = 0; i < MI; ++i)
#pragma unroll
    for (int j = 0; j < 4; ++j) acc[i][j] = (f32x4){0.f, 0.f, 0.f, 0.f};

  const int lrow = lane >> 2;   // row within 16-row wave chunk
  const int lkg  = lane & 3;

  for (int k0 = 0; k0 < K; k0 += 32) {
#pragma unroll
    for (int j = 0; j < 2; ++j) {          // A tile: 128 rows
      int row = w * 16 + j * 64 + lrow;
      int kgs = lkg ^ ((row >> 1) & 3);
      __builtin_amdgcn_global_load_lds(
        (const __attribute__((address_space(1))) unsigned*)(Xp + (long)row * K + k0 + kgs * 8),
        (__attribute__((address_space(3))) unsigned*)(sA + (w * 16 + j * 64) * 32),
        16, 0, 0);
    }
#pragma unroll
    for (int j = 0; j < BN / 64; ++j) {    // B tile: BN rows
      int row = w * 16 + j * 64 + lrow;
      int kgs = lkg ^ ((row >> 1) & 3);
      __builtin_amdgcn_global_load_lds(
        (const __attribute__((address_space(1))) unsigned*)(Wp + (long)row * K + k0 + kgs * 8),
        (__attribute__((address_space(3))) unsigned*)(sB + (w * 16 + j * 64) * 32),
        16, 0, 0);
    }
    __syncthreads();
    s16x8 af[MI], bfr[4];
#pragma unroll
    for (int mi = 0; mi < MI; ++mi) {
      int row = wm * (MI * 16) + mi * 16 + (lane & 15);
      int kg = (lane >> 4) ^ ((row >> 1) & 3);
      af[mi] = *(const s16x8*)((const char*)sA + row * 64 + kg * 16);
    }
#pragma unroll
    for (int ni = 0; ni < 4; ++ni) {
      int row = wn * 64 + ni * 16 + (lane & 15);
      int kg = (lane >> 4) ^ ((row >> 1) & 3);
      bfr[ni] = *(const s16x8*)((const char*)sB + row * 64 + kg * 16);
    }
#pragma unroll
    for (int mi = 0; mi < MI; ++mi)
#pragma unroll
      for (int ni = 0; ni < 4; ++ni)
        acc[mi][ni] = mfma16(af[mi], bfr[ni], acc[mi][ni]);
    __syncthreads();
  }

  const int col0 = lane & 15;
  const int rsub = (lane >> 4) * 4;
#pragma unroll
  for (int mi = 0; mi < MI; ++mi) {
    int row = m0 + wm * (MI * 16) + mi * 16 + rsub;
#pragma unroll
    for (int ni = 0; ni < 4; ++ni) {
      int col = n0 + wn * 64 + ni * 16 + col0;
#pragma unroll
      for (int j = 0; j < 4; ++j) {
        float v = acc[mi][ni][j];
        int r = row + j;
        if constexpr (EPI == 0) {
          outF[(long)d * sOutF + (long)r * N + col] = v;
        } else if constexpr (EPI == 1) {
          int d2 = col >> 11, cc = col & 2047;
          long o = ((long)d2 * NTOK + r) * DI;
          if (cc < DI) outB[o + cc] = f2bf(v);
          else         outB2[o + cc - DI] = f2bf(v);
        } else if constexpr (EPI == 3) {
          float t = v + bias[col];
          float u3 = t * (1.f + 0.044715f * t * t);
          float sg = __builtin_amdgcn_rcpf(1.f + __builtin_amdgcn_exp2f(-2.3022083f * u3));
          outB[(long)r * N + col] = f2bf(t * sg);
        } else if constexpr (EPI == 4) {
          outF[(long)r * N + col] = v + bias[col] + res[(long)r * N + col];
        } else if constexpr (EPI == 5) {
          if (col < 32) outB[((long)d * NTOK + r) * 32 + col] = f2bf(v);
          else          outF[((long)d * NTOK + r) * 64 + col] = v;
        }
      }
    }
  }
}

extern "C" void kernel_launch(void* const* d_in, const int* in_sizes, int n_in,
                              void* d_out, int out_size, void* d_ws, size_t ws_size,
                              hipStream_t stream) {
  const float* x      = (const float*)d_in[0];
  const float* gamma1 = (const float*)d_in[1];
  const float* beta1  = (const float*)d_in[2];
  const float* W_in   = (const float*)d_in[3];
  const float* conv_w = (const float*)d_in[4];
  const float* conv_b = (const float*)d_in[5];
  const float* W_xprj = (const float*)d_in[6];
  const float* W_dt   = (const float*)d_in[7];
  const float* b_dt   = (const float*)d_in[8];
  const float* A_log  = (const float*)d_in[9];
  const float* Dp     = (const float*)d_in[10];
  const float* W_out  = (const float*)d_in[11];
  const float* gamma2 = (const float*)d_in[12];
  const float* beta2  = (const float*)d_in[13];
  const float* W1     = (const float*)d_in[14];
  const float* b1     = (const float*)d_in[15];
  const float* W2     = (const float*)d_in[16];
  const float* b2     = (const float*)d_in[17];
  float* out = (float*)d_out;

  char* ws = (char*)d_ws;
  short* wb_in  = (short*)(ws);                              // 4 MB
  short* wb_xp  = (short*)(ws + (4L << 20));                 // 256 KB
  short* wb_dt  = (short*)(ws + (4L << 20) + (256L << 10));  // 128 KB
  short* wb_out = (short*)(ws + (4L << 20) + (384L << 10));  // 2 MB
  short* wb_w1  = (short*)(ws + (6L << 20) + (384L << 10));  // 2 MB
  short* wb_w2  = (short*)(ws + (8L << 20) + (384L << 10));  // 2 MB
  short* xnbf = (short*)(ws + (12L << 20));   // 8 MB; later xln
  short* ubuf = (short*)(ws + (20L << 20));   // 32 MB (d,n,ch) raw u
  short* zbuf = (short*)(ws + (52L << 20));   // 32 MB; later yo f32
  short* ucv  = (short*)(ws + (84L << 20));   // 32 MB conv-out; y in-place
  short* Hbuf = (short*)(ws + (116L << 20));  // 32 MB MLP hidden
  float* xdbl = (float*)(ws + (148L << 20));  // 4 MB
  short* dtr  = (short*)(ws + (152L << 20));  // 1 MB
  float* hbuf = (float*)(ws + (153L << 20));  // 16 MB
  float* Sbuf = (float*)(ws + (169L << 20));  // 1 MB
  float* xmid = (float*)(ws + (170L << 20));  // 16 MB -> ends 186 MB
  float* yo   = (float*)zbuf;
  short* xln  = xnbf;

  // 0. pre-cast weights to bf16
  castw_kernel<<<2048, 256, 0, stream>>>(W_in,   wb_in,  2097152);
  castw_kernel<<<128,  256, 0, stream>>>(W_xprj, wb_xp,  131072);
  castw_kernel<<<64,   256, 0, stream>>>(W_dt,   wb_dt,  65536);
  castw_kernel<<<1024, 256, 0, stream>>>(W_out,  wb_out, 1048576);
  castw_kernel<<<1024, 256, 0, stream>>>(W1,     wb_w1,  1048576);
  castw_kernel<<<1024, 256, 0, stream>>>(W2,     wb_w2,  1048576);
  // 1. LN1 -> bf16
  ln1_kernel<<<NTOK / 4, 256, 0, stream>>>(x, gamma1, beta1, xnbf);
  // 2. in_proj both dirs: u -> ubuf, z -> zbuf (both (d,n,ch) bf16)
  gemm_m97<1, 128><<<dim3(64, 32, 1), 256, 0, stream>>>(
      xnbf, 0, wb_in, 0, nullptr, 0, nullptr, 0, ubuf, nullptr, zbuf, C_, 4096);
  // 3. conv + silu -> ucv
  conv_silu_kernel<<<dim3(4, 16, 8), 256, 0, stream>>>(ubuf, conv_w, conv_b, ucv);
  // 4. x_proj: dtr bf16 + xdbl f32
  gemm_m97<5, 64><<<dim3(64, 1, 2), 256, 0, stream>>>(
      ucv, SLICE, wb_xp, 64L * DI, nullptr, 0, xdbl, 0, dtr, nullptr, nullptr, DI, 64);
  // 5-7. chunked scan with fused dt (mini-MFMA per block)
  scan_pass<0, 0><<<dim3(4, NC_, 4), 256, 0, stream>>>(dtr, wb_dt, b_dt, ucv, xdbl, zbuf, A_log, Dp, hbuf, Sbuf, ucv);
  scan_pass<0, 1><<<dim3(4, NC_, 4), 256, 0, stream>>>(dtr, wb_dt, b_dt, ucv, xdbl, zbuf, A_log, Dp, hbuf, Sbuf, ucv);
  scan_combine<<<32, 256, 0, stream>>>(A_log, hbuf, Sbuf);
  scan_pass<1, 0><<<dim3(4, NC_, 4), 256, 0, stream>>>(dtr, wb_dt, b_dt, ucv, xdbl, zbuf, A_log, Dp, hbuf, Sbuf, ucv);
  scan_pass<1, 1><<<dim3(4, NC_, 4), 256, 0, stream>>>(dtr, wb_dt, b_dt, ucv, xdbl, zbuf, A_log, Dp, hbuf, Sbuf, ucv);
  // 8. out_proj -> yo f32 (over consumed zbuf)
  gemm_m97<0, 128><<<dim3(64, 4, 2), 256, 0, stream>>>(
      ucv, SLICE, wb_out, (long)C_ * DI, nullptr, 0, yo, (long)NTOK * C_, nullptr,
      nullptr, nullptr, DI, C_);
  // 9. residual combine + LN2
  combine_ln2_kernel<<<NTOK / 4, 256, 0, stream>>>(x, yo, gamma2, beta2, xmid, xln);
  // 10. MLP up + gelu -> Hbuf bf16
  gemm_m97<3, 128><<<dim3(64, 16, 1), 256, 0, stream>>>(
      xln, 0, wb_w1, 0, b1, 0, nullptr, 0, Hbuf, nullptr, nullptr, C_, 2048);
  // 11. MLP down + bias + residual -> out f32
  gemm_m97<4, 128><<<dim3(64, 4, 1), 256, 0, stream>>>(
      Hbuf, 0, wb_w2, 0, b2, 0, out, 0, nullptr, xmid, nullptr, 2048, C_);
}